// Round 1
// baseline (470.451 us; speedup 1.0000x reference)
//
#include <hip/hip_runtime.h>

typedef float f32x4 __attribute__((ext_vector_type(4)));
typedef __bf16 bf16x8 __attribute__((ext_vector_type(8)));
typedef unsigned short u16;
typedef unsigned int u32;
typedef u32 u32x4 __attribute__((ext_vector_type(4)));

#define SEQ 2048
#define DMODEL 1024
#define NH 16
#define MTOT 8192   // B*S
#define NQKV 3072

__device__ __forceinline__ u16 f2bf(float f) {
  u32 u = __builtin_bit_cast(u32, f);
  u = (u + 0x7fffu + ((u >> 16) & 1u)) >> 16;
  return (u16)u;
}

__device__ __forceinline__ void gl_lds16(const void* g, void* l) {
  __builtin_amdgcn_global_load_lds(
      (const __attribute__((address_space(1))) u32*)g,
      (__attribute__((address_space(3))) u32*)l, 16, 0, 0);
}

// ---------------- fp32 -> bf16 conversion of X and W_all ----------------
__global__ __launch_bounds__(256) void cvt_kernel(
    const float* __restrict__ X, const float* __restrict__ Wq,
    const float* __restrict__ Wk, const float* __restrict__ Wv,
    u16* __restrict__ Xb, u16* __restrict__ Wall) {
  const long NX = (long)MTOT * DMODEL;    // 8388608
  const long NW = (long)DMODEL * DMODEL;  // 1048576 = 2^20
  long i = ((long)blockIdx.x * 256 + threadIdx.x) * 4;
  if (i < NX) {
    float4 v = *reinterpret_cast<const float4*>(X + i);
    u16* dst = Xb + i;
    dst[0] = f2bf(v.x); dst[1] = f2bf(v.y); dst[2] = f2bf(v.z); dst[3] = f2bf(v.w);
  } else {
    long j = i - NX;
    if (j < 3 * NW) {
      long wsel = j >> 20;
      long k = j & (NW - 1);
      const float* src = wsel == 0 ? Wq : (wsel == 1 ? Wk : Wv);
      float4 v = *reinterpret_cast<const float4*>(src + k);
      u16* dst = Wall + j;
      dst[0] = f2bf(v.x); dst[1] = f2bf(v.y); dst[2] = f2bf(v.z); dst[3] = f2bf(v.w);
    }
  }
}

// ---------------- fused QKV projection GEMM ----------------
// A [8192][1024] bf16 (k-contig), Bw [3072][1024] bf16 (k-contig = W layout),
// C [8192][3072] bf16.  C[m][n] = sum_k A[m][k]*Bw[n][k] + bias[n]
__global__ __launch_bounds__(256) void gemm_qkv(
    const u16* __restrict__ A, const u16* __restrict__ Bw,
    const float* __restrict__ bq, const float* __restrict__ bk,
    const float* __restrict__ bv, u16* __restrict__ C) {
  __shared__ __align__(16) u16 As[128 * 32];
  __shared__ __align__(16) u16 Bs[128 * 32];
  const int t = threadIdx.x;
  const int l = t & 63, w = t >> 6;
  const int wr = w >> 1, wc = w & 1;
  const int g16 = l >> 4, l16 = l & 15;
  const long m0 = (long)blockIdx.x * 128;
  const long n0 = (long)blockIdx.y * 128;
  f32x4 acc[4][4] = {};

  const int rA = w * 16 + (l >> 2);  // + is*64 -> row 0..127
  const int cA = (l & 3) * 8;        // bf16 col within 32

  for (int k0 = 0; k0 < DMODEL; k0 += 32) {
#pragma unroll
    for (int is = 0; is < 2; ++is) {
      gl_lds16(A + (m0 + is * 64 + rA) * DMODEL + k0 + cA,
               (char*)As + is * 4096 + w * 1024);
      gl_lds16(Bw + (n0 + is * 64 + rA) * DMODEL + k0 + cA,
               (char*)Bs + is * 4096 + w * 1024);
    }
    __syncthreads();
    bf16x8 af[4], bf[4];
#pragma unroll
    for (int i = 0; i < 4; ++i)
      af[i] = *reinterpret_cast<const bf16x8*>(
          (const char*)As + (wr * 64 + i * 16 + l16) * 64 + g16 * 16);
#pragma unroll
    for (int j = 0; j < 4; ++j)
      bf[j] = *reinterpret_cast<const bf16x8*>(
          (const char*)Bs + (wc * 64 + j * 16 + l16) * 64 + g16 * 16);
#pragma unroll
    for (int i = 0; i < 4; ++i)
#pragma unroll
      for (int j = 0; j < 4; ++j)
        acc[i][j] = __builtin_amdgcn_mfma_f32_16x16x32_bf16(af[i], bf[j], acc[i][j], 0, 0, 0);
    __syncthreads();
  }

#pragma unroll
  for (int j = 0; j < 4; ++j) {
    const long n = n0 + wc * 64 + j * 16 + l16;
    const float bias = n < 1024 ? bq[n] : (n < 2048 ? bk[n - 1024] : bv[n - 2048]);
#pragma unroll
    for (int i = 0; i < 4; ++i) {
      const long m = m0 + wr * 64 + i * 16 + g16 * 4;
#pragma unroll
      for (int r = 0; r < 4; ++r)
        C[(m + r) * NQKV + n] = f2bf(acc[i][j][r] + bias);
    }
  }
}

// ---------------- flash attention ----------------
// QKV [8192][3072] bf16: cols [0,1024)=Q, [1024,2048)=K, [2048,3072)=V, head h at h*64.
// grid: x=32 q-tiles (64 rows each), y=64 (b*16+h). 4 waves/block, 16 q-rows/wave.
__global__ __launch_bounds__(256) void attn_kernel(
    const u16* __restrict__ QKV, const float* __restrict__ mask,
    float* __restrict__ out) {
  __shared__ __align__(16) u16 Ks[64 * 64];    // [k][d] swizzled
  __shared__ __align__(16) u16 Vts[64 * 64];   // [d][k] swizzled
  __shared__ __align__(16) u16 Ps[4][16 * 64]; // per-wave P tile [q][k] swizzled
  const int qt = blockIdx.x;
  const int bh = blockIdx.y;
  const int b = bh >> 4, h = bh & 15;
  const int t = threadIdx.x;
  const int l = t & 63, w = t >> 6;
  const int g16 = l >> 4, l16 = l & 15;

  // Q fragments (held in registers for the whole kernel)
  bf16x8 qf[2];
  {
    const long qrow = (long)SEQ * b + qt * 64 + w * 16 + l16;
#pragma unroll
    for (int kh = 0; kh < 2; ++kh)
      qf[kh] = *reinterpret_cast<const bf16x8*>(
          QKV + qrow * NQKV + h * 64 + kh * 32 + g16 * 8);
  }

  float m_[4], l_[4];
  f32x4 c_[4] = {};
#pragma unroll
  for (int r = 0; r < 4; ++r) { m_[r] = -INFINITY; l_[r] = 0.f; }

  const int sr = t >> 3;         // staging row 0..31
  const int scol = (t & 7) * 8;  // staging col base (elements)

  for (int kt = 0; kt < 32; ++kt) {
    // ---- stage K tile and transposed V tile ----
#pragma unroll
    for (int half = 0; half < 2; ++half) {
      const int kk = half * 32 + sr;
      const long grow = (long)SEQ * b + kt * 64 + kk;
      const u16* gk = QKV + grow * NQKV + 1024 + h * 64 + scol;
      u32x4 kv = *reinterpret_cast<const u32x4*>(gk);
      *reinterpret_cast<u32x4*>((char*)Ks + kk * 128 + ((scol * 2) ^ ((kk & 7) << 4))) = kv;
      u32x4 vv = *reinterpret_cast<const u32x4*>(gk + 1024);
#pragma unroll
      for (int jj = 0; jj < 4; ++jj) {
        const u32 pair = vv[jj];
        const int d0 = scol + jj * 2;
        *reinterpret_cast<u16*>((char*)Vts + (d0 + 0) * 128 + ((kk * 2) ^ (((d0 + 0) & 7) << 4))) = (u16)(pair & 0xffffu);
        *reinterpret_cast<u16*>((char*)Vts + (d0 + 1) * 128 + ((kk * 2) ^ (((d0 + 1) & 7) << 4))) = (u16)(pair >> 16);
      }
    }
    __syncthreads();

    // ---- S = Q K^T ----
    f32x4 s[4];
#pragma unroll
    for (int kt16 = 0; kt16 < 4; ++kt16) {
      f32x4 sv = {0.f, 0.f, 0.f, 0.f};
      const int krow = kt16 * 16 + l16;
#pragma unroll
      for (int kh = 0; kh < 2; ++kh) {
        bf16x8 kf = *reinterpret_cast<const bf16x8*>(
            (const char*)Ks + krow * 128 + ((kh * 64 + g16 * 16) ^ ((krow & 7) << 4)));
        sv = __builtin_amdgcn_mfma_f32_16x16x32_bf16(qf[kh], kf, sv, 0, 0, 0);
      }
      s[kt16] = sv;
    }

    // ---- online softmax ----
    float p[4][4], rm[4], rs[4];
#pragma unroll
    for (int r = 0; r < 4; ++r) rm[r] = -INFINITY;
#pragma unroll
    for (int kt16 = 0; kt16 < 4; ++kt16) {
      const float mv = mask[(long)SEQ * b + kt * 64 + kt16 * 16 + l16];
#pragma unroll
      for (int r = 0; r < 4; ++r) {
        p[kt16][r] = s[kt16][r] * 0.125f + mv;
        rm[r] = fmaxf(rm[r], p[kt16][r]);
      }
    }
#pragma unroll
    for (int mm = 1; mm < 16; mm <<= 1)
#pragma unroll
      for (int r = 0; r < 4; ++r)
        rm[r] = fmaxf(rm[r], __shfl_xor(rm[r], mm, 64));
#pragma unroll
    for (int r = 0; r < 4; ++r) {
      const float mn = fmaxf(m_[r], rm[r]);
      const float scale = __expf(m_[r] - mn);
      m_[r] = mn;
      l_[r] *= scale;
#pragma unroll
      for (int dt = 0; dt < 4; ++dt) c_[dt][r] *= scale;
      rs[r] = 0.f;
#pragma unroll
      for (int kt16 = 0; kt16 < 4; ++kt16) {
        p[kt16][r] = __expf(p[kt16][r] - mn);
        rs[r] += p[kt16][r];
      }
    }
#pragma unroll
    for (int mm = 1; mm < 16; mm <<= 1)
#pragma unroll
      for (int r = 0; r < 4; ++r)
        rs[r] += __shfl_xor(rs[r], mm, 64);
#pragma unroll
    for (int r = 0; r < 4; ++r) l_[r] += rs[r];

    // ---- P -> LDS (bf16) ----
#pragma unroll
    for (int kt16 = 0; kt16 < 4; ++kt16)
#pragma unroll
      for (int r = 0; r < 4; ++r) {
        const int prow = g16 * 4 + r;
        const int pcol = kt16 * 16 + l16;
        *reinterpret_cast<u16*>(
            (char*)Ps[w] + prow * 128 + ((pcol * 2) ^ ((prow & 7) << 4))) = f2bf(p[kt16][r]);
      }
    asm volatile("s_waitcnt lgkmcnt(0)" ::: "memory");

    // ---- ctx += P V ----
#pragma unroll
    for (int kh = 0; kh < 2; ++kh) {
      bf16x8 pa = *reinterpret_cast<const bf16x8*>(
          (const char*)Ps[w] + l16 * 128 + ((kh * 64 + g16 * 16) ^ ((l16 & 7) << 4)));
#pragma unroll
      for (int dt = 0; dt < 4; ++dt) {
        const int vrow = dt * 16 + l16;
        bf16x8 vb = *reinterpret_cast<const bf16x8*>(
            (const char*)Vts + vrow * 128 + ((kh * 64 + g16 * 16) ^ ((vrow & 7) << 4)));
        c_[dt] = __builtin_amdgcn_mfma_f32_16x16x32_bf16(pa, vb, c_[dt], 0, 0, 0);
      }
    }
    __syncthreads();
  }

  // ---- epilogue: divide by softmax denom, write fp32 output ----
  const long srow = (long)SEQ * b + qt * 64 + w * 16 + g16 * 4;
#pragma unroll
  for (int dt = 0; dt < 4; ++dt) {
    const int d = dt * 16 + l16;
#pragma unroll
    for (int r = 0; r < 4; ++r)
      out[(srow + r) * DMODEL + h * 64 + d] = c_[dt][r] / l_[r];
  }
}

extern "C" void kernel_launch(void* const* d_in, const int* in_sizes, int n_in,
                              void* d_out, int out_size, void* d_ws, size_t ws_size,
                              hipStream_t stream) {
  const float* X    = (const float*)d_in[0];
  const float* mask = (const float*)d_in[1];
  const float* Wq   = (const float*)d_in[2];
  const float* bq   = (const float*)d_in[3];
  const float* Wk   = (const float*)d_in[4];
  const float* bk   = (const float*)d_in[5];
  const float* Wv   = (const float*)d_in[6];
  const float* bv   = (const float*)d_in[7];
  float* out = (float*)d_out;

  char* ws = (char*)d_ws;
  u16* Xb   = (u16*)ws;                                   // 16 MiB
  u16* Wall = (u16*)(ws + (16ull << 20));                 // 6 MiB
  u16* QKV  = (u16*)(ws + (16ull << 20) + (6ull << 20));  // 48 MiB

  cvt_kernel<<<11264, 256, 0, stream>>>(X, Wq, Wk, Wv, Xb, Wall);
  gemm_qkv<<<dim3(64, 24), 256, 0, stream>>>(Xb, Wall, bq, bk, bv, QKV);
  attn_kernel<<<dim3(32, 64), 256, 0, stream>>>(QKV, mask, out);
}

// Round 2
// 343.635 us; speedup vs baseline: 1.3690x; 1.3690x over previous
//
#include <hip/hip_runtime.h>

typedef float f32x4 __attribute__((ext_vector_type(4)));
typedef __bf16 bf16x8 __attribute__((ext_vector_type(8)));
typedef unsigned short u16;
typedef unsigned int u32;
typedef u32 u32x4 __attribute__((ext_vector_type(4)));

#define SEQ 2048
#define DMODEL 1024
#define MTOT 8192   // B*S
#define NQKV 3072
#define LOG2E 1.4426950408889634f
#define C1 0.18033688011112042f  // 0.125 * log2(e)

__device__ __forceinline__ u16 f2bf(float f) {
  u32 u = __builtin_bit_cast(u32, f);
  u = (u + 0x7fffu + ((u >> 16) & 1u)) >> 16;
  return (u16)u;
}

__device__ __forceinline__ void gl_lds16(const void* g, void* l) {
  __builtin_amdgcn_global_load_lds(
      (const __attribute__((address_space(1))) u32*)g,
      (__attribute__((address_space(3))) u32*)l, 16, 0, 0);
}

// ---------------- fp32 -> bf16 conversion of X, W_all; mask*log2e ----------------
__global__ __launch_bounds__(256) void cvt_kernel(
    const float* __restrict__ X, const float* __restrict__ Wq,
    const float* __restrict__ Wk, const float* __restrict__ Wv,
    const float* __restrict__ mask,
    u16* __restrict__ Xb, u16* __restrict__ Wall, float* __restrict__ mskL) {
  const long NX = (long)MTOT * DMODEL;    // 8388608
  const long NW = (long)DMODEL * DMODEL;  // 1048576 = 2^20
  long i = ((long)blockIdx.x * 256 + threadIdx.x) * 4;
  if (i < NX) {
    float4 v = *reinterpret_cast<const float4*>(X + i);
    u16* dst = Xb + i;
    dst[0] = f2bf(v.x); dst[1] = f2bf(v.y); dst[2] = f2bf(v.z); dst[3] = f2bf(v.w);
  } else {
    long j = i - NX;
    if (j < 3 * NW) {
      long wsel = j >> 20;
      long k = j & (NW - 1);
      const float* src = wsel == 0 ? Wq : (wsel == 1 ? Wk : Wv);
      float4 v = *reinterpret_cast<const float4*>(src + k);
      u16* dst = Wall + j;
      dst[0] = f2bf(v.x); dst[1] = f2bf(v.y); dst[2] = f2bf(v.z); dst[3] = f2bf(v.w);
    } else {
      long jm = j - 3 * NW;
      if (jm < (long)4 * SEQ) {
        float4 v = *reinterpret_cast<const float4*>(mask + jm);
        float4 o = {v.x * LOG2E, v.y * LOG2E, v.z * LOG2E, v.w * LOG2E};
        *reinterpret_cast<float4*>(mskL + jm) = o;
      }
    }
  }
}

// ---------------- fused QKV projection GEMM (unchanged, m97-style) ----------------
__global__ __launch_bounds__(256) void gemm_qkv(
    const u16* __restrict__ A, const u16* __restrict__ Bw,
    const float* __restrict__ bq, const float* __restrict__ bk,
    const float* __restrict__ bv, u16* __restrict__ C) {
  __shared__ __align__(16) u16 As[128 * 32];
  __shared__ __align__(16) u16 Bs[128 * 32];
  const int t = threadIdx.x;
  const int l = t & 63, w = t >> 6;
  const int wr = w >> 1, wc = w & 1;
  const int g16 = l >> 4, l16 = l & 15;
  const long m0 = (long)blockIdx.x * 128;
  const long n0 = (long)blockIdx.y * 128;
  f32x4 acc[4][4] = {};

  const int rA = w * 16 + (l >> 2);
  const int cA = (l & 3) * 8;

  for (int k0 = 0; k0 < DMODEL; k0 += 32) {
#pragma unroll
    for (int is = 0; is < 2; ++is) {
      gl_lds16(A + (m0 + is * 64 + rA) * DMODEL + k0 + cA,
               (char*)As + is * 4096 + w * 1024);
      gl_lds16(Bw + (n0 + is * 64 + rA) * DMODEL + k0 + cA,
               (char*)Bs + is * 4096 + w * 1024);
    }
    __syncthreads();
    bf16x8 af[4], bf[4];
#pragma unroll
    for (int i = 0; i < 4; ++i)
      af[i] = *reinterpret_cast<const bf16x8*>(
          (const char*)As + (wr * 64 + i * 16 + l16) * 64 + g16 * 16);
#pragma unroll
    for (int j = 0; j < 4; ++j)
      bf[j] = *reinterpret_cast<const bf16x8*>(
          (const char*)Bs + (wc * 64 + j * 16 + l16) * 64 + g16 * 16);
#pragma unroll
    for (int i = 0; i < 4; ++i)
#pragma unroll
      for (int j = 0; j < 4; ++j)
        acc[i][j] = __builtin_amdgcn_mfma_f32_16x16x32_bf16(af[i], bf[j], acc[i][j], 0, 0, 0);
    __syncthreads();
  }

#pragma unroll
  for (int j = 0; j < 4; ++j) {
    const long n = n0 + wc * 64 + j * 16 + l16;
    const float bias = n < 1024 ? bq[n] : (n < 2048 ? bk[n - 1024] : bv[n - 2048]);
#pragma unroll
    for (int i = 0; i < 4; ++i) {
      const long m = m0 + wr * 64 + i * 16 + g16 * 4;
#pragma unroll
      for (int r = 0; r < 4; ++r)
        C[(m + r) * NQKV + n] = f2bf(acc[i][j][r] + bias);
    }
  }
}

// ---------------- flash attention v2: swapped QK^T, conflict-free LDS ----------------
// grid: x=32 q-tiles (64 rows), y=64 (b*16+h). 4 waves, 16 q/wave (q = l&15).
__global__ __launch_bounds__(256) void attn_kernel(
    const u16* __restrict__ QKV, const float* __restrict__ mskL,
    float* __restrict__ out) {
  // K: [64 k][8 chunk][8 elems], chunk' = chunk ^ (k&7)  (per-row XOR swizzle)
  // V: [64 d][8 chunk][8 elems] of V^T, chunk' = (k>>3) ^ (((d>>3)^d)&7)
  __shared__ __align__(16) u16 Ks[2][64 * 64];
  __shared__ __align__(16) u16 Vs[2][64 * 64];
  __shared__ __align__(16) float Mv[2][64];
  __shared__ __align__(16) u16 Pt[4][64 * 18];  // per-wave P^T [k][q], stride 18

  const int qt = blockIdx.x, bh = blockIdx.y;
  const int b = bh >> 4, h = bh & 15;
  const int t = threadIdx.x, l = t & 63, w = t >> 6;
  const int l15 = l & 15, g16 = l >> 4;

  const u16* Qg = QKV + (long)b * SEQ * NQKV + h * 64;
  const u16* Kg = Qg + 1024;
  const u16* Vg = Qg + 2048;
  const float* Mg = mskL + (long)b * SEQ;

  // Q fragments (B-operand: lane l15 = q-row, elems d-slice g16*8)
  bf16x8 qf[2];
  {
    const long qr = (long)(qt * 64 + w * 16 + l15) * NQKV + g16 * 8;
    qf[0] = *reinterpret_cast<const bf16x8*>(Qg + qr);
    qf[1] = *reinterpret_cast<const bf16x8*>(Qg + qr + 32);
  }

  // per-lane staging addresses (tile-invariant offsets)
  const int srow = w * 8 + (l >> 3);                 // row within 32-half
  const u16* kp0 = Kg + (long)srow * NQKV + (((l & 7) ^ (l >> 3)) * 8);
  const u16* kp1 = kp0 + (long)32 * NQKV;
  const u16* vp0 = Vg + (long)srow * NQKV + (l & 7) * 8;
  const u16* vp1 = vp0 + (long)32 * NQKV;
  u16* ksDst0 = Ks[0] + w * 512;   // bytes w*1024; half1 at +2048 elems
  u16* ksDst1 = Ks[1] + w * 512;

  // V write constants: off(k,d) = d*128 + ((k>>3 ^ ((d>>3)^d)&7)&7)*16 + (k&7)*2
  const int vbase = (l & 7) * 1024 + (l >> 3) * 2;   // scol*128 + klo*2 (bytes)

  // K read chunk offsets (per kh, lane-const): ((kh*4+g16) ^ (l15&7))&7 << 4
  const int kx0 = (((g16) ^ (l15 & 7)) & 7) << 4;
  const int kx1 = (((4 + g16) ^ (l15 & 7)) & 7) << 4;

  float m_ = -INFINITY, l_ = 0.f;
  f32x4 c_[4] = {};

  // ---- prologue: stage tile 0 ----
  {
    u32x4 a0 = *reinterpret_cast<const u32x4*>(vp0);
    u32x4 a1 = *reinterpret_cast<const u32x4*>(vp1);
    gl_lds16(kp0, ksDst0);
    gl_lds16(kp1, ksDst0 + 2048);
    if (t < 16) gl_lds16(Mg + t * 4, Mv[0]);
    char* VsB = (char*)Vs[0];
#pragma unroll
    for (int half = 0; half < 2; ++half) {
      const u32x4 vv = half ? a1 : a0;
      const int cx = (half * 4 + w) ^ (l & 7);
#pragma unroll
      for (int jj = 0; jj < 4; ++jj) {
        const int c0 = (cx ^ (2 * jj)) & 7;
        const u32 pair = vv[jj];
        *(u16*)(VsB + vbase + jj * 256 + (c0 << 4)) = (u16)pair;
        *(u16*)(VsB + vbase + jj * 256 + 128 + ((c0 ^ 1) << 4)) = (u16)(pair >> 16);
      }
    }
  }
  __syncthreads();

  int cb = 0;
  for (int kt = 0; kt < 32; ++kt) {
    // ---- issue next-tile loads (T14 issue-early) ----
    u32x4 b0, b1;
    const bool pref = kt < 31;
    if (pref) {
      const long adv = (long)(kt + 1) * 64 * NQKV;
      b0 = *reinterpret_cast<const u32x4*>(vp0 + adv);
      b1 = *reinterpret_cast<const u32x4*>(vp1 + adv);
      u16* kd = (cb ? ksDst0 : ksDst1);
      gl_lds16(kp0 + adv, kd);
      gl_lds16(kp1 + adv, kd + 2048);
      if (t < 16) gl_lds16(Mg + (kt + 1) * 64 + t * 4, Mv[cb ^ 1]);
    }

    // ---- S^T = K Q^T ----
    const char* KsB = (const char*)Ks[cb];
    f32x4 s4[4] = {};
#pragma unroll
    for (int kt16 = 0; kt16 < 4; ++kt16) {
      const char* rowp = KsB + (kt16 * 16 + l15) * 128;
      bf16x8 k0 = *reinterpret_cast<const bf16x8*>(rowp + kx0);
      bf16x8 k1 = *reinterpret_cast<const bf16x8*>(rowp + kx1);
      s4[kt16] = __builtin_amdgcn_mfma_f32_16x16x32_bf16(k0, qf[0], s4[kt16], 0, 0, 0);
      s4[kt16] = __builtin_amdgcn_mfma_f32_16x16x32_bf16(k1, qf[1], s4[kt16], 0, 0, 0);
    }

    // ---- online softmax (lane q = l15, values in-lane) ----
    float z[16];
    float mx = -INFINITY;
#pragma unroll
    for (int kt16 = 0; kt16 < 4; ++kt16) {
      f32x4 mv4 = *reinterpret_cast<const f32x4*>(&Mv[cb][kt16 * 16 + g16 * 4]);
#pragma unroll
      for (int r = 0; r < 4; ++r) {
        const float zz = s4[kt16][r] * C1 + mv4[r];
        z[kt16 * 4 + r] = zz;
        mx = fmaxf(mx, zz);
      }
    }
    mx = fmaxf(mx, __shfl_xor(mx, 16, 64));
    mx = fmaxf(mx, __shfl_xor(mx, 32, 64));
    const float mn = fmaxf(m_, mx);
    const float sc = __builtin_amdgcn_exp2f(m_ - mn);
    m_ = mn;
    float rs = 0.f;
#pragma unroll
    for (int i = 0; i < 16; ++i) {
      const float p = __builtin_amdgcn_exp2f(z[i] - mn);
      z[i] = p;
      rs += p;
    }
    rs += __shfl_xor(rs, 16, 64);
    rs += __shfl_xor(rs, 32, 64);
    l_ = l_ * sc + rs;
#pragma unroll
    for (int dt = 0; dt < 4; ++dt) {
      c_[dt][0] *= sc; c_[dt][1] *= sc; c_[dt][2] *= sc; c_[dt][3] *= sc;
    }

    // ---- P^T -> per-wave LDS [k][q] stride 18 ----
    __bf16* PtW = (__bf16*)Pt[w];
#pragma unroll
    for (int kt16 = 0; kt16 < 4; ++kt16)
#pragma unroll
      for (int r = 0; r < 4; ++r)
        PtW[(kt16 * 16 + g16 * 4 + r) * 18 + l15] = (__bf16)z[kt16 * 4 + r];

    // ---- O^T += V^T P^T ----
    const char* VsB = (const char*)Vs[cb];
#pragma unroll
    for (int kh = 0; kh < 2; ++kh) {
      bf16x8 pb;
#pragma unroll
      for (int e = 0; e < 8; ++e)
        pb[e] = PtW[(kh * 32 + g16 * 8 + e) * 18 + l15];
#pragma unroll
      for (int dt = 0; dt < 4; ++dt) {
        const int d = dt * 16 + l15;
        const int fd = ((d >> 3) ^ d) & 7;
        bf16x8 va = *reinterpret_cast<const bf16x8*>(
            VsB + d * 128 + ((((kh * 4 + g16) ^ fd) & 7) << 4));
        c_[dt] = __builtin_amdgcn_mfma_f32_16x16x32_bf16(va, pb, c_[dt], 0, 0, 0);
      }
    }

    // ---- write next V tile (T14 write-late), then barrier ----
    if (pref) {
      char* VsN = (char*)Vs[cb ^ 1];
#pragma unroll
      for (int half = 0; half < 2; ++half) {
        const u32x4 vv = half ? b1 : b0;
        const int cx = (half * 4 + w) ^ (l & 7);
#pragma unroll
        for (int jj = 0; jj < 4; ++jj) {
          const int c0 = (cx ^ (2 * jj)) & 7;
          const u32 pair = vv[jj];
          *(u16*)(VsN + vbase + jj * 256 + (c0 << 4)) = (u16)pair;
          *(u16*)(VsN + vbase + jj * 256 + 128 + ((c0 ^ 1) << 4)) = (u16)(pair >> 16);
        }
      }
    }
    __syncthreads();
    cb ^= 1;
  }

  // ---- epilogue: normalize, write fp32 out (coalesces to full 64B lines) ----
  const float inv = 1.0f / l_;
  const long orow = ((long)b * SEQ + qt * 64 + w * 16 + l15) * DMODEL + h * 64;
#pragma unroll
  for (int dt = 0; dt < 4; ++dt) {
    f32x4 o = {c_[dt][0] * inv, c_[dt][1] * inv, c_[dt][2] * inv, c_[dt][3] * inv};
    *reinterpret_cast<f32x4*>(out + orow + dt * 16 + g16 * 4) = o;
  }
}

extern "C" void kernel_launch(void* const* d_in, const int* in_sizes, int n_in,
                              void* d_out, int out_size, void* d_ws, size_t ws_size,
                              hipStream_t stream) {
  const float* X    = (const float*)d_in[0];
  const float* mask = (const float*)d_in[1];
  const float* Wq   = (const float*)d_in[2];
  const float* bq   = (const float*)d_in[3];
  const float* Wk   = (const float*)d_in[4];
  const float* bk   = (const float*)d_in[5];
  const float* Wv   = (const float*)d_in[6];
  const float* bv   = (const float*)d_in[7];
  float* out = (float*)d_out;

  char* ws = (char*)d_ws;
  u16* Xb    = (u16*)ws;                                   // 16 MiB
  u16* Wall  = (u16*)(ws + (16ull << 20));                 // 6 MiB
  u16* QKV   = (u16*)(ws + (16ull << 20) + (6ull << 20));  // 48 MiB
  float* mskL = (float*)(ws + (70ull << 20));              // 32 KiB

  cvt_kernel<<<11272, 256, 0, stream>>>(X, Wq, Wk, Wv, mask, Xb, Wall, mskL);
  gemm_qkv<<<dim3(64, 24), 256, 0, stream>>>(Xb, Wall, bq, bk, bv, QKV);
  attn_kernel<<<dim3(32, 64), 256, 0, stream>>>(QKV, mskL, out);
}

// Round 3
// 322.725 us; speedup vs baseline: 1.4577x; 1.0648x over previous
//
#include <hip/hip_runtime.h>

typedef float f32x4 __attribute__((ext_vector_type(4)));
typedef __bf16 bf16x8 __attribute__((ext_vector_type(8)));
typedef __bf16 bf16x4 __attribute__((ext_vector_type(4)));
typedef unsigned short u16;
typedef unsigned int u32;

#define SEQ 2048
#define DMODEL 1024
#define MTOT 8192   // B*S
#define LOG2E 1.4426950408889634f
#define C1 0.18033688011112042f  // 0.125 * log2(e)

__device__ __forceinline__ void gl_lds16(const void* g, void* l) {
  __builtin_amdgcn_global_load_lds(
      (const __attribute__((address_space(1))) u32*)g,
      (__attribute__((address_space(3))) u32*)l, 16, 0, 0);
}

// ---------------- fp32 -> bf16 conversion of X, W_all; mask*log2e ----------------
__global__ __launch_bounds__(256) void cvt_kernel(
    const float* __restrict__ X, const float* __restrict__ Wq,
    const float* __restrict__ Wk, const float* __restrict__ Wv,
    const float* __restrict__ mask,
    u16* __restrict__ Xb, u16* __restrict__ Wall, float* __restrict__ mskL) {
  const long NX = (long)MTOT * DMODEL;    // 8388608
  const long NW = (long)DMODEL * DMODEL;  // 1048576 = 2^20
  long i = ((long)blockIdx.x * 256 + threadIdx.x) * 4;
  if (i < NX) {
    float4 v = *reinterpret_cast<const float4*>(X + i);
    bf16x4 o = {(__bf16)v.x, (__bf16)v.y, (__bf16)v.z, (__bf16)v.w};
    *reinterpret_cast<bf16x4*>(Xb + i) = o;
  } else {
    long j = i - NX;
    if (j < 3 * NW) {
      long wsel = j >> 20;
      long k = j & (NW - 1);
      const float* src = wsel == 0 ? Wq : (wsel == 1 ? Wk : Wv);
      float4 v = *reinterpret_cast<const float4*>(src + k);
      bf16x4 o = {(__bf16)v.x, (__bf16)v.y, (__bf16)v.z, (__bf16)v.w};
      *reinterpret_cast<bf16x4*>(Wall + j) = o;
    } else {
      long jm = j - 3 * NW;
      if (jm < (long)4 * SEQ) {
        float4 v = *reinterpret_cast<const float4*>(mask + jm);
        float4 o = {v.x * LOG2E, v.y * LOG2E, v.z * LOG2E, v.w * LOG2E};
        *reinterpret_cast<float4*>(mskL + jm) = o;
      }
    }
  }
}

// ---------------- Q/K projection GEMM (swapped operands, packed stores) --------
// A [8192][1024] bf16, Bw = Wall rows [0,2048). Writes Qb/Kb [8192][1024].
__global__ __launch_bounds__(256) void gemm_qk(
    const u16* __restrict__ A, const u16* __restrict__ Bw,
    const float* __restrict__ bq, const float* __restrict__ bk,
    u16* __restrict__ Qb, u16* __restrict__ Kb) {
  __shared__ __align__(16) u16 As[128 * 32];
  __shared__ __align__(16) u16 Bs[128 * 32];
  const int t = threadIdx.x;
  const int l = t & 63, w = t >> 6;
  const int wr = w >> 1, wc = w & 1;
  const int g16 = l >> 4, l15 = l & 15;
  const long m0 = (long)blockIdx.x * 128;
  const long n0 = (long)blockIdx.y * 128;
  f32x4 acc[4][4] = {};

  const int rA = w * 16 + (l >> 2);
  const int cA = (l & 3) * 8;

  for (int k0 = 0; k0 < DMODEL; k0 += 32) {
#pragma unroll
    for (int is = 0; is < 2; ++is) {
      gl_lds16(A + (m0 + is * 64 + rA) * DMODEL + k0 + cA,
               (char*)As + is * 4096 + w * 1024);
      gl_lds16(Bw + (n0 + is * 64 + rA) * DMODEL + k0 + cA,
               (char*)Bs + is * 4096 + w * 1024);
    }
    __syncthreads();
    bf16x8 af[4], bf[4];
#pragma unroll
    for (int i = 0; i < 4; ++i)
      af[i] = *reinterpret_cast<const bf16x8*>(
          (const char*)As + (wr * 64 + i * 16 + l15) * 64 + g16 * 16);
#pragma unroll
    for (int j = 0; j < 4; ++j)
      bf[j] = *reinterpret_cast<const bf16x8*>(
          (const char*)Bs + (wc * 64 + j * 16 + l15) * 64 + g16 * 16);
#pragma unroll
    for (int i = 0; i < 4; ++i)
#pragma unroll
      for (int j = 0; j < 4; ++j)  // swapped: output row = n-sub, col = m-sub
        acc[i][j] = __builtin_amdgcn_mfma_f32_16x16x32_bf16(bf[j], af[i], acc[i][j], 0, 0, 0);
    __syncthreads();
  }

  const bool isQ = n0 < 1024;
  const float* bias = isQ ? bq : bk;
  u16* Cb = isQ ? Qb : Kb;
  const long nb = isQ ? n0 : n0 - 1024;
#pragma unroll
  for (int j = 0; j < 4; ++j) {
    const int nq = wc * 64 + j * 16 + g16 * 4;  // n quad base within 128-tile
    f32x4 bv4 = *reinterpret_cast<const f32x4*>(bias + nb + nq);
#pragma unroll
    for (int i = 0; i < 4; ++i) {
      const long m = m0 + wr * 64 + i * 16 + l15;
      bf16x4 pk = {(__bf16)(acc[i][j][0] + bv4[0]), (__bf16)(acc[i][j][1] + bv4[1]),
                   (__bf16)(acc[i][j][2] + bv4[2]), (__bf16)(acc[i][j][3] + bv4[3])};
      *reinterpret_cast<bf16x4*>(Cb + m * 1024 + nb + nq) = pk;
    }
  }
}

// ---------------- V projection GEMM (normal orientation, transposed output) ----
// Bw = Wall rows [2048,3072). Writes Vt [64 bh][64 d][2048 s].
__global__ __launch_bounds__(256) void gemm_v(
    const u16* __restrict__ A, const u16* __restrict__ Bw,
    const float* __restrict__ bv, u16* __restrict__ Vt) {
  __shared__ __align__(16) u16 As[128 * 32];
  __shared__ __align__(16) u16 Bs[128 * 32];
  const int t = threadIdx.x;
  const int l = t & 63, w = t >> 6;
  const int wr = w >> 1, wc = w & 1;
  const int g16 = l >> 4, l15 = l & 15;
  const long m0 = (long)blockIdx.x * 128;
  const long n0 = (long)blockIdx.y * 128;
  f32x4 acc[4][4] = {};

  const int rA = w * 16 + (l >> 2);
  const int cA = (l & 3) * 8;

  for (int k0 = 0; k0 < DMODEL; k0 += 32) {
#pragma unroll
    for (int is = 0; is < 2; ++is) {
      gl_lds16(A + (m0 + is * 64 + rA) * DMODEL + k0 + cA,
               (char*)As + is * 4096 + w * 1024);
      gl_lds16(Bw + (n0 + is * 64 + rA) * DMODEL + k0 + cA,
               (char*)Bs + is * 4096 + w * 1024);
    }
    __syncthreads();
    bf16x8 af[4], bf[4];
#pragma unroll
    for (int i = 0; i < 4; ++i)
      af[i] = *reinterpret_cast<const bf16x8*>(
          (const char*)As + (wr * 64 + i * 16 + l15) * 64 + g16 * 16);
#pragma unroll
    for (int j = 0; j < 4; ++j)
      bf[j] = *reinterpret_cast<const bf16x8*>(
          (const char*)Bs + (wc * 64 + j * 16 + l15) * 64 + g16 * 16);
#pragma unroll
    for (int i = 0; i < 4; ++i)
#pragma unroll
      for (int j = 0; j < 4; ++j)  // normal: row = m-sub, col = n-sub
        acc[i][j] = __builtin_amdgcn_mfma_f32_16x16x32_bf16(af[i], bf[j], acc[i][j], 0, 0, 0);
    __syncthreads();
  }

#pragma unroll
  for (int j = 0; j < 4; ++j) {
    const int dg = (int)n0 + wc * 64 + j * 16 + l15;  // 0..1023
    const float bias = bv[dg];
    const int h = dg >> 6, dd = dg & 63;
#pragma unroll
    for (int i = 0; i < 4; ++i) {
      const long m = m0 + wr * 64 + i * 16 + g16 * 4;  // quad of consecutive s
      const long b = m >> 11, s = m & 2047;
      bf16x4 pk = {(__bf16)(acc[i][j][0] + bias), (__bf16)(acc[i][j][1] + bias),
                   (__bf16)(acc[i][j][2] + bias), (__bf16)(acc[i][j][3] + bias)};
      *reinterpret_cast<bf16x4*>(Vt + ((b * 16 + h) * 64 + dd) * 2048 + s) = pk;
    }
  }
}

// ---------------- flash attention v3 ----------------
// grid: x=32 q-tiles (64 rows), y=64 (b*16+h). 4 waves, 16 q/wave (q = l&15).
__global__ __launch_bounds__(256) void attn_kernel(
    const u16* __restrict__ Qb, const u16* __restrict__ Kb,
    const u16* __restrict__ Vt, const float* __restrict__ mskL,
    float* __restrict__ out) {
  // Ks: [64 k][8 d-chunk][8], pos = chunk ^ (k&7)
  // Vs: [64 d][8 k-chunk][8], pos = chunk ^ (d&7)   (V^T tile)
  __shared__ __align__(16) u16 Ks[2][64 * 64];
  __shared__ __align__(16) u16 Vs[2][64 * 64];
  __shared__ __align__(16) float Mv[2][64];
  __shared__ __align__(16) u16 Pt[4][16 * 72];  // per-wave P [q][k], stride 72

  const int qt = blockIdx.x, bh = blockIdx.y;
  const int b = bh >> 4, h = bh & 15;
  const int t = threadIdx.x, l = t & 63, w = t >> 6;
  const int l15 = l & 15, g16 = l >> 4;

  // Q fragments
  bf16x8 qf0, qf1;
  {
    const u16* Qg = Qb + ((long)b * SEQ + qt * 64 + w * 16 + l15) * 1024 + h * 64 + g16 * 8;
    qf0 = *reinterpret_cast<const bf16x8*>(Qg);
    qf1 = *reinterpret_cast<const bf16x8*>(Qg + 32);
  }

  // staging sources (pre-swizzled so linear LDS dest = swizzled layout)
  const int swz = ((l & 7) ^ (l >> 3)) * 8;
  const u16* kp0 = Kb + ((long)b * SEQ + w * 8 + (l >> 3)) * 1024 + h * 64 + swz;
  const u16* kp1 = kp0 + (long)32 * 1024;
  const u16* vp0 = Vt + ((long)bh * 64 + w * 16 + (l >> 3)) * 2048 + swz;
  const u16* vp1 = vp0 + (long)8 * 2048;
  const float* Mg = mskL + (long)b * SEQ;

  float m_ = -INFINITY, l_ = 0.f;
  f32x4 c_[4] = {};

#define STAGE(buf, kt)                                              \
  {                                                                 \
    const long ka = (long)(kt) * 64 * 1024;                         \
    const long va = (long)(kt) * 64;                                \
    gl_lds16(kp0 + ka, Ks[buf] + w * 512);                          \
    gl_lds16(kp1 + ka, Ks[buf] + w * 512 + 2048);                   \
    gl_lds16(vp0 + va, Vs[buf] + w * 1024);                         \
    gl_lds16(vp1 + va, Vs[buf] + w * 1024 + 512);                   \
    if (t < 16) gl_lds16(Mg + (kt) * 64 + t * 4, Mv[buf]);          \
  }

  STAGE(0, 0);
  __syncthreads();

  int cb = 0;
  for (int kt = 0; kt < 32; ++kt) {
    if (kt < 31) STAGE(cb ^ 1, kt + 1);

    // ---- S^T = K Q^T ----
    const char* KsB = (const char*)Ks[cb];
    const int kx0 = ((g16 ^ (l15 & 7)) & 7) << 4;
    const int kx1 = (((4 + g16) ^ (l15 & 7)) & 7) << 4;
    f32x4 s4[4] = {};
    __builtin_amdgcn_s_setprio(1);
#pragma unroll
    for (int kt16 = 0; kt16 < 4; ++kt16) {
      const char* rowp = KsB + (kt16 * 16 + l15) * 128;
      bf16x8 k0 = *reinterpret_cast<const bf16x8*>(rowp + kx0);
      bf16x8 k1 = *reinterpret_cast<const bf16x8*>(rowp + kx1);
      s4[kt16] = __builtin_amdgcn_mfma_f32_16x16x32_bf16(k0, qf0, s4[kt16], 0, 0, 0);
      s4[kt16] = __builtin_amdgcn_mfma_f32_16x16x32_bf16(k1, qf1, s4[kt16], 0, 0, 0);
    }
    __builtin_amdgcn_s_setprio(0);

    // ---- online softmax (lane q = l15; 16 k-values in-lane) ----
    float z[16];
    float mx = -INFINITY;
#pragma unroll
    for (int kt16 = 0; kt16 < 4; ++kt16) {
      f32x4 mv4 = *reinterpret_cast<const f32x4*>(&Mv[cb][kt16 * 16 + g16 * 4]);
#pragma unroll
      for (int r = 0; r < 4; ++r) {
        const float zz = s4[kt16][r] * C1 + mv4[r];
        z[kt16 * 4 + r] = zz;
        mx = fmaxf(mx, zz);
      }
    }
    mx = fmaxf(mx, __shfl_xor(mx, 16, 64));
    mx = fmaxf(mx, __shfl_xor(mx, 32, 64));
    if (!__all(mx <= m_ + 8.0f)) {  // T13 defer-max
      const float mn = fmaxf(m_, mx);
      const float sc = __builtin_amdgcn_exp2f(m_ - mn);
      m_ = mn;
      l_ *= sc;
#pragma unroll
      for (int dt = 0; dt < 4; ++dt) {
        c_[dt][0] *= sc; c_[dt][1] *= sc; c_[dt][2] *= sc; c_[dt][3] *= sc;
      }
    }
    float rs = 0.f;
#pragma unroll
    for (int i = 0; i < 16; ++i) {
      const float p = __builtin_amdgcn_exp2f(z[i] - m_);
      z[i] = p;
      rs += p;
    }
    rs += __shfl_xor(rs, 16, 64);
    rs += __shfl_xor(rs, 32, 64);
    l_ += rs;

    // ---- P -> LDS [q=l15][72], 4x packed 8B writes ----
    u16* Pw = Pt[w];
#pragma unroll
    for (int kt16 = 0; kt16 < 4; ++kt16) {
      bf16x4 pv = {(__bf16)z[kt16 * 4 + 0], (__bf16)z[kt16 * 4 + 1],
                   (__bf16)z[kt16 * 4 + 2], (__bf16)z[kt16 * 4 + 3]};
      *reinterpret_cast<bf16x4*>(Pw + l15 * 72 + kt16 * 16 + g16 * 4) = pv;
    }
    asm volatile("s_waitcnt lgkmcnt(0)" ::: "memory");
    __builtin_amdgcn_sched_barrier(0);

    // ---- O^T += V^T P^T ----
    const char* VsB = (const char*)Vs[cb];
    __builtin_amdgcn_s_setprio(1);
#pragma unroll
    for (int kh = 0; kh < 2; ++kh) {
      bf16x8 pb = *reinterpret_cast<const bf16x8*>(Pw + l15 * 72 + kh * 32 + g16 * 8);
#pragma unroll
      for (int dt = 0; dt < 4; ++dt) {
        const int d = dt * 16 + l15;
        bf16x8 va = *reinterpret_cast<const bf16x8*>(
            VsB + d * 128 + ((((kh * 4 + g16) ^ (d & 7)) & 7) << 4));
        c_[dt] = __builtin_amdgcn_mfma_f32_16x16x32_bf16(va, pb, c_[dt], 0, 0, 0);
      }
    }
    __builtin_amdgcn_s_setprio(0);
    __syncthreads();
    cb ^= 1;
  }

  // ---- epilogue ----
  const float inv = 1.0f / l_;
  const long orow = ((long)b * SEQ + qt * 64 + w * 16 + l15) * DMODEL + h * 64;
#pragma unroll
  for (int dt = 0; dt < 4; ++dt) {
    f32x4 o = {c_[dt][0] * inv, c_[dt][1] * inv, c_[dt][2] * inv, c_[dt][3] * inv};
    *reinterpret_cast<f32x4*>(out + orow + dt * 16 + g16 * 4) = o;
  }
}

extern "C" void kernel_launch(void* const* d_in, const int* in_sizes, int n_in,
                              void* d_out, int out_size, void* d_ws, size_t ws_size,
                              hipStream_t stream) {
  const float* X    = (const float*)d_in[0];
  const float* mask = (const float*)d_in[1];
  const float* Wq   = (const float*)d_in[2];
  const float* bq   = (const float*)d_in[3];
  const float* Wk   = (const float*)d_in[4];
  const float* bk   = (const float*)d_in[5];
  const float* Wv   = (const float*)d_in[6];
  const float* bv   = (const float*)d_in[7];
  float* out = (float*)d_out;

  char* ws = (char*)d_ws;
  u16* Xb    = (u16*)ws;                        // 16 MiB
  u16* Wall  = (u16*)(ws + (16ull << 20));      // 6 MiB
  u16* Qb    = (u16*)(ws + (22ull << 20));      // 16 MiB
  u16* Kb    = (u16*)(ws + (38ull << 20));      // 16 MiB
  u16* Vt    = (u16*)(ws + (54ull << 20));      // 16 MiB [64 bh][64 d][2048 s]
  float* mskL = (float*)(ws + (70ull << 20));   // 32 KiB

  cvt_kernel<<<11272, 256, 0, stream>>>(X, Wq, Wk, Wv, mask, Xb, Wall, mskL);
  gemm_qk<<<dim3(64, 16), 256, 0, stream>>>(Xb, Wall, bq, bk, Qb, Kb);
  gemm_v<<<dim3(64, 8), 256, 0, stream>>>(Xb, Wall + (long)2048 * 1024, bv, Vt);
  attn_kernel<<<dim3(32, 64), 256, 0, stream>>>(Qb, Kb, Vt, mskL, out);
}

// Round 5
// 302.945 us; speedup vs baseline: 1.5529x; 1.0653x over previous
//
#include <hip/hip_runtime.h>

typedef float f32x4 __attribute__((ext_vector_type(4)));
typedef __bf16 bf16x8 __attribute__((ext_vector_type(8)));
typedef __bf16 bf16x4 __attribute__((ext_vector_type(4)));
typedef unsigned short u16;
typedef unsigned int u32;

#define SEQ 2048
#define DMODEL 1024
#define MTOT 8192   // B*S
#define LOG2E 1.4426950408889634f
#define C1 0.18033688011112042f  // 0.125 * log2(e)

__device__ __forceinline__ void gl_lds16(const void* g, void* l) {
  __builtin_amdgcn_global_load_lds(
      (const __attribute__((address_space(1))) u32*)g,
      (__attribute__((address_space(3))) u32*)l, 16, 0, 0);
}

// ---------------- fp32 -> bf16 conversion of X, W_all; mask*log2e ----------------
__global__ __launch_bounds__(256) void cvt_kernel(
    const float* __restrict__ X, const float* __restrict__ Wq,
    const float* __restrict__ Wk, const float* __restrict__ Wv,
    const float* __restrict__ mask,
    u16* __restrict__ Xb, u16* __restrict__ Wall, float* __restrict__ mskL) {
  const long NX = (long)MTOT * DMODEL;    // 8388608
  const long NW = (long)DMODEL * DMODEL;  // 1048576 = 2^20
  long i = ((long)blockIdx.x * 256 + threadIdx.x) * 4;
  if (i < NX) {
    float4 v = *reinterpret_cast<const float4*>(X + i);
    bf16x4 o = {(__bf16)v.x, (__bf16)v.y, (__bf16)v.z, (__bf16)v.w};
    *reinterpret_cast<bf16x4*>(Xb + i) = o;
  } else {
    long j = i - NX;
    if (j < 3 * NW) {
      long wsel = j >> 20;
      long k = j & (NW - 1);
      const float* src = wsel == 0 ? Wq : (wsel == 1 ? Wk : Wv);
      float4 v = *reinterpret_cast<const float4*>(src + k);
      bf16x4 o = {(__bf16)v.x, (__bf16)v.y, (__bf16)v.z, (__bf16)v.w};
      *reinterpret_cast<bf16x4*>(Wall + j) = o;
    } else {
      long jm = j - 3 * NW;
      if (jm < (long)4 * SEQ) {
        float4 v = *reinterpret_cast<const float4*>(mask + jm);
        float4 o = {v.x * LOG2E, v.y * LOG2E, v.z * LOG2E, v.w * LOG2E};
        *reinterpret_cast<float4*>(mskL + jm) = o;
      }
    }
  }
}

// ---------------- fused QKV projection GEMM ----------------
// by<16: Q/K (swapped-operand mfma, packed [m][1024] stores)
// by>=16: V (normal mfma, transposed store Vt [64 bh][64 d][2048 s])
__global__ __launch_bounds__(256) void gemm_qkv(
    const u16* __restrict__ A, const u16* __restrict__ Wall,
    const float* __restrict__ bq, const float* __restrict__ bk,
    const float* __restrict__ bv,
    u16* __restrict__ Qb, u16* __restrict__ Kb, u16* __restrict__ Vt) {
  __shared__ __align__(16) u16 As[128 * 32];
  __shared__ __align__(16) u16 Bs[128 * 32];
  const int id = blockIdx.x;                  // 1536 blocks
  const int vid = (id & 7) * 192 + (id >> 3); // bijective XCD chunking (m204)
  const int bx = vid & 63, by = vid >> 6;     // bx: m-tile 0..63, by: n-tile 0..23
  const int t = threadIdx.x;
  const int l = t & 63, w = t >> 6;
  const int wr = w >> 1, wc = w & 1;
  const int g16 = l >> 4, l15 = l & 15;
  const long m0 = (long)bx * 128;
  const long n0 = (long)by * 128;
  const bool isV = by >= 16;
  f32x4 acc[4][4] = {};

  const int rA = w * 16 + (l >> 2);
  const int cA = (l & 3) * 8;
  const u16* Bw = Wall + n0 * 1024;

  for (int k0 = 0; k0 < DMODEL; k0 += 32) {
#pragma unroll
    for (int is = 0; is < 2; ++is) {
      gl_lds16(A + (m0 + is * 64 + rA) * DMODEL + k0 + cA,
               (char*)As + is * 4096 + w * 1024);
      gl_lds16(Bw + ((long)is * 64 + rA) * DMODEL + k0 + cA,
               (char*)Bs + is * 4096 + w * 1024);
    }
    __syncthreads();
    bf16x8 af[4], bf[4];
#pragma unroll
    for (int i = 0; i < 4; ++i)
      af[i] = *reinterpret_cast<const bf16x8*>(
          (const char*)As + (wr * 64 + i * 16 + l15) * 64 + g16 * 16);
#pragma unroll
    for (int j = 0; j < 4; ++j)
      bf[j] = *reinterpret_cast<const bf16x8*>(
          (const char*)Bs + (wc * 64 + j * 16 + l15) * 64 + g16 * 16);
    if (isV) {
#pragma unroll
      for (int i = 0; i < 4; ++i)
#pragma unroll
        for (int j = 0; j < 4; ++j)
          acc[i][j] = __builtin_amdgcn_mfma_f32_16x16x32_bf16(af[i], bf[j], acc[i][j], 0, 0, 0);
    } else {
#pragma unroll
      for (int i = 0; i < 4; ++i)
#pragma unroll
        for (int j = 0; j < 4; ++j)
          acc[i][j] = __builtin_amdgcn_mfma_f32_16x16x32_bf16(bf[j], af[i], acc[i][j], 0, 0, 0);
    }
    __syncthreads();
  }

  if (!isV) {
    const bool isQ = n0 < 1024;
    const float* bias = isQ ? bq : bk;
    u16* Cb = isQ ? Qb : Kb;
    const long nb = isQ ? n0 : n0 - 1024;
#pragma unroll
    for (int j = 0; j < 4; ++j) {
      const int nq = wc * 64 + j * 16 + g16 * 4;
      f32x4 bv4 = *reinterpret_cast<const f32x4*>(bias + nb + nq);
#pragma unroll
      for (int i = 0; i < 4; ++i) {
        const long m = m0 + wr * 64 + i * 16 + l15;
        bf16x4 pk = {(__bf16)(acc[i][j][0] + bv4[0]), (__bf16)(acc[i][j][1] + bv4[1]),
                     (__bf16)(acc[i][j][2] + bv4[2]), (__bf16)(acc[i][j][3] + bv4[3])};
        *reinterpret_cast<bf16x4*>(Cb + m * 1024 + nb + nq) = pk;
      }
    }
  } else {
#pragma unroll
    for (int j = 0; j < 4; ++j) {
      const int dg = (int)(n0 - 2048) + wc * 64 + j * 16 + l15;  // 0..1023
      const float bias = bv[dg];
      const int h = dg >> 6, dd = dg & 63;
#pragma unroll
      for (int i = 0; i < 4; ++i) {
        const long m = m0 + wr * 64 + i * 16 + g16 * 4;
        const long b = m >> 11, s = m & 2047;
        bf16x4 pk = {(__bf16)(acc[i][j][0] + bias), (__bf16)(acc[i][j][1] + bias),
                     (__bf16)(acc[i][j][2] + bias), (__bf16)(acc[i][j][3] + bias)};
        *reinterpret_cast<bf16x4*>(Vt + ((b * 16 + h) * 64 + dd) * 2048 + s) = pk;
      }
    }
  }
}

// ---------------- flash attention v4 ----------------
// 1D grid 2048, XCD-chunked: each XCD owns 8 bh values (K/V L2-local).
// 4 waves, 16 q/wave (q = l&15). LDS exactly 40960B -> 4 blocks/CU.
__global__ __launch_bounds__(256) void attn_kernel(
    const u16* __restrict__ Qb, const u16* __restrict__ Kb,
    const u16* __restrict__ Vt, const float* __restrict__ mskL,
    float* __restrict__ out) {
  __shared__ __align__(16) u16 Ks[2][64 * 64];  // [k][8 chunk][8], chunk^=(k&7)
  __shared__ __align__(16) u16 Vs[2][64 * 64];  // [d][8 chunk][8], chunk^=(d&7)
  __shared__ __align__(16) u16 Pt[4][16 * 64];  // per-wave [q][8 chunk][8], chunk^=(q&7)

  const int id = blockIdx.x;
  const int bh = (id & 7) * 8 + (id >> 8);
  const int qt = (id >> 3) & 31;
  const int b = bh >> 4, h = bh & 15;
  const int t = threadIdx.x, l = t & 63, w = t >> 6;
  const int l15 = l & 15, g16 = l >> 4;

  bf16x8 qf0, qf1;
  {
    const u16* Qg = Qb + ((long)b * SEQ + qt * 64 + w * 16 + l15) * 1024 + h * 64 + g16 * 8;
    qf0 = *reinterpret_cast<const bf16x8*>(Qg);
    qf1 = *reinterpret_cast<const bf16x8*>(Qg + 32);
  }

  const int swz = ((l & 7) ^ (l >> 3)) * 8;
  const u16* kp0 = Kb + ((long)b * SEQ + w * 8 + (l >> 3)) * 1024 + h * 64 + swz;
  const u16* kp1 = kp0 + (long)32 * 1024;
  const u16* vp0 = Vt + ((long)bh * 64 + w * 16 + (l >> 3)) * 2048 + swz;
  const u16* vp1 = vp0 + (long)8 * 2048;
  const float* Mg = mskL + (long)b * SEQ;

  float m_ = -INFINITY, l_ = 0.f;
  f32x4 c_[4] = {};
  f32x4 mreg[4], mnext[4];

#define STAGE(buf, kt)                                              \
  {                                                                 \
    const long ka = (long)(kt) * 64 * 1024;                         \
    const long va = (long)(kt) * 64;                                \
    gl_lds16(kp0 + ka, Ks[buf] + w * 512);                          \
    gl_lds16(kp1 + ka, Ks[buf] + w * 512 + 2048);                   \
    gl_lds16(vp0 + va, Vs[buf] + w * 1024);                         \
    gl_lds16(vp1 + va, Vs[buf] + w * 1024 + 512);                   \
  }

  STAGE(0, 0);
#pragma unroll
  for (int kt16 = 0; kt16 < 4; ++kt16)
    mreg[kt16] = *reinterpret_cast<const f32x4*>(Mg + kt16 * 16 + g16 * 4);
  __syncthreads();

  int cb = 0;
  for (int kt = 0; kt < 32; ++kt) {
    if (kt < 31) {
      STAGE(cb ^ 1, kt + 1);
#pragma unroll
      for (int kt16 = 0; kt16 < 4; ++kt16)
        mnext[kt16] = *reinterpret_cast<const f32x4*>(Mg + (kt + 1) * 64 + kt16 * 16 + g16 * 4);
    }

    // ---- S^T = K Q^T ----
    const char* KsB = (const char*)Ks[cb];
    const int kx0 = ((g16 ^ (l15 & 7)) & 7) << 4;
    const int kx1 = (((4 + g16) ^ (l15 & 7)) & 7) << 4;
    f32x4 s4[4] = {};
    __builtin_amdgcn_s_setprio(1);
#pragma unroll
    for (int kt16 = 0; kt16 < 4; ++kt16) {
      const char* rowp = KsB + (kt16 * 16 + l15) * 128;
      bf16x8 k0 = *reinterpret_cast<const bf16x8*>(rowp + kx0);
      bf16x8 k1 = *reinterpret_cast<const bf16x8*>(rowp + kx1);
      s4[kt16] = __builtin_amdgcn_mfma_f32_16x16x32_bf16(k0, qf0, s4[kt16], 0, 0, 0);
      s4[kt16] = __builtin_amdgcn_mfma_f32_16x16x32_bf16(k1, qf1, s4[kt16], 0, 0, 0);
    }
    __builtin_amdgcn_s_setprio(0);

    // ---- online softmax (lane q = l15; 16 k-values in-lane) ----
    float z[16];
    float mx = -INFINITY;
#pragma unroll
    for (int kt16 = 0; kt16 < 4; ++kt16)
#pragma unroll
      for (int r = 0; r < 4; ++r) {
        const float zz = s4[kt16][r] * C1 + mreg[kt16][r];
        z[kt16 * 4 + r] = zz;
        mx = fmaxf(mx, zz);
      }
    if (!__all(mx <= m_ + 8.0f)) {  // T13 defer-max (reduce only when triggered)
      mx = fmaxf(mx, __shfl_xor(mx, 16, 64));
      mx = fmaxf(mx, __shfl_xor(mx, 32, 64));
      const float mn = fmaxf(m_, mx);
      const float sc = __builtin_amdgcn_exp2f(m_ - mn);
      m_ = mn;
      l_ *= sc;
#pragma unroll
      for (int dt = 0; dt < 4; ++dt) {
        c_[dt][0] *= sc; c_[dt][1] *= sc; c_[dt][2] *= sc; c_[dt][3] *= sc;
      }
    }
    float rs = 0.f;
#pragma unroll
    for (int i = 0; i < 16; ++i) {
      const float p = __builtin_amdgcn_exp2f(z[i] - m_);
      z[i] = p;
      rs += p;
    }
    l_ += rs;  // per-lane partial; reduced once at epilogue

    // ---- P -> per-wave LDS, stride-64, XOR-16B swizzle ----
    char* Pw = (char*)Pt[w];
#pragma unroll
    for (int kt16 = 0; kt16 < 4; ++kt16) {
      bf16x4 pv = {(__bf16)z[kt16 * 4 + 0], (__bf16)z[kt16 * 4 + 1],
                   (__bf16)z[kt16 * 4 + 2], (__bf16)z[kt16 * 4 + 3]};
      *reinterpret_cast<bf16x4*>(
          Pw + l15 * 128 + ((((kt16 * 2 + (g16 >> 1)) ^ (l15 & 7)) & 7) << 4) + (g16 & 1) * 8) = pv;
    }
    asm volatile("s_waitcnt lgkmcnt(0)" ::: "memory");
    __builtin_amdgcn_sched_barrier(0);

    // ---- O^T += V^T P^T ----
    const char* VsB = (const char*)Vs[cb];
    __builtin_amdgcn_s_setprio(1);
#pragma unroll
    for (int kh = 0; kh < 2; ++kh) {
      bf16x8 pb = *reinterpret_cast<const bf16x8*>(
          Pw + l15 * 128 + ((((kh * 4 + g16) ^ (l15 & 7)) & 7) << 4));
#pragma unroll
      for (int dt = 0; dt < 4; ++dt) {
        const int d = dt * 16 + l15;
        bf16x8 va = *reinterpret_cast<const bf16x8*>(
            VsB + d * 128 + ((((kh * 4 + g16) ^ (d & 7)) & 7) << 4));
        c_[dt] = __builtin_amdgcn_mfma_f32_16x16x32_bf16(va, pb, c_[dt], 0, 0, 0);
      }
    }
    __builtin_amdgcn_s_setprio(0);

#pragma unroll
    for (int kt16 = 0; kt16 < 4; ++kt16) mreg[kt16] = mnext[kt16];
    __syncthreads();
    cb ^= 1;
  }

  // ---- epilogue: reduce l_ across the 4 k-groups, normalize, store ----
  l_ += __shfl_xor(l_, 16, 64);
  l_ += __shfl_xor(l_, 32, 64);
  const float inv = 1.0f / l_;
  const long orow = ((long)b * SEQ + qt * 64 + w * 16 + l15) * DMODEL + h * 64;
#pragma unroll
  for (int dt = 0; dt < 4; ++dt) {
    f32x4 o = {c_[dt][0] * inv, c_[dt][1] * inv, c_[dt][2] * inv, c_[dt][3] * inv};
    *reinterpret_cast<f32x4*>(out + orow + dt * 16 + g16 * 4) = o;
  }
}

extern "C" void kernel_launch(void* const* d_in, const int* in_sizes, int n_in,
                              void* d_out, int out_size, void* d_ws, size_t ws_size,
                              hipStream_t stream) {
  const float* X    = (const float*)d_in[0];
  const float* mask = (const float*)d_in[1];
  const float* Wq   = (const float*)d_in[2];
  const float* bq   = (const float*)d_in[3];
  const float* Wk   = (const float*)d_in[4];
  const float* bk   = (const float*)d_in[5];
  const float* Wv   = (const float*)d_in[6];
  const float* bv   = (const float*)d_in[7];
  float* out = (float*)d_out;

  char* ws = (char*)d_ws;
  u16* Xb    = (u16*)ws;                        // 16 MiB
  u16* Wall  = (u16*)(ws + (16ull << 20));      // 6 MiB
  u16* Qb    = (u16*)(ws + (22ull << 20));      // 16 MiB
  u16* Kb    = (u16*)(ws + (38ull << 20));      // 16 MiB
  u16* Vt    = (u16*)(ws + (54ull << 20));      // 16 MiB [64 bh][64 d][2048 s]
  float* mskL = (float*)(ws + (70ull << 20));   // 32 KiB

  cvt_kernel<<<11272, 256, 0, stream>>>(X, Wq, Wk, Wv, mask, Xb, Wall, mskL);
  gemm_qkv<<<1536, 256, 0, stream>>>(Xb, Wall, bq, bk, bv, Qb, Kb, Vt);
  attn_kernel<<<2048, 256, 0, stream>>>(Qb, Kb, Vt, mskL, out);
}